// Round 11
// baseline (4772.626 us; speedup 1.0000x reference)
//
#include <hip/hip_runtime.h>

typedef __attribute__((ext_vector_type(8))) short short8;
typedef __attribute__((ext_vector_type(4))) float f32x4;
typedef __attribute__((ext_vector_type(4))) _Float16 f16x4;
typedef __attribute__((ext_vector_type(4))) unsigned int u32x4;
typedef unsigned long long u64_t;

#define DI __device__ __forceinline__

// ---------------- helpers ----------------
DI unsigned short f2bf(float f) {            // RNE float->bf16
  unsigned int u = __float_as_uint(f);
  u += 0x7FFFu + ((u >> 16) & 1u);
  return (unsigned short)(u >> 16);
}

DI void gload_lds16(const void* g, void* l) { // async global->LDS, 16B/lane
  __builtin_amdgcn_global_load_lds(
      (const __attribute__((address_space(1))) unsigned int*)g,
      (__attribute__((address_space(3))) unsigned int*)l, 16, 0, 0);
}

DI float sigm(float x) { return 1.f / (1.f + __expf(-x)); }
DI float tanh_(float x) { return 1.f - 2.f / (__expf(2.f * x) + 1.f); }

// LLC-coherent (sc0 sc1) exchange ops — scope proven correct rounds 2-4/6/7/10
DI unsigned flag_load(const unsigned int* p) {
  unsigned r;
  asm volatile("global_load_dword %0, %1, off sc0 sc1\n\ts_waitcnt vmcnt(0)"
               : "=v"(r) : "v"(p) : "memory");
  return r;
}
DI u32x4 h_load16(const void* p) {  // no waitcnt: caller drains once
  u32x4 r;
  asm volatile("global_load_dwordx4 %0, %1, off sc0 sc1" : "=v"(r) : "v"(p) : "memory");
  return r;
}
DI void h_store4(void* p, unsigned v) {
  asm volatile("global_store_dword %0, %1, off sc0 sc1" :: "v"(p), "v"(v) : "memory");
}

// bounded LDS seq-flag spin (intra-WG point-to-point sync)
DI void lds_spin(volatile unsigned* p, unsigned tgt) {
  for (int i = 0; i < (1 << 22); ++i) {
    if (*p >= tgt) break;
  }
  asm volatile("" ::: "memory");
  __builtin_amdgcn_sched_barrier(0);
}

// ---------------- sizes / workspace layout ----------------
// B=64 C=800 T=512 H=1024 IN=1600 4H=4096 TB=32768
static constexpr size_t OFF_WXT  = 0;                       // bf16 [4096][1600]
static constexpr size_t OFF_WHT  = 13107200;                // bf16 [4096][1024]
static constexpr size_t OFF_BSUM = OFF_WHT + 8388608;       // f32  [4096] (bx+bh)
static constexpr size_t OFF_XS   = OFF_BSUM + 16384;        // u32  [32768][800]
static constexpr size_t OFF_GX   = OFF_XS + 104857600;      // f16  [32768][4096] (col-permuted)
static constexpr size_t OFF_HBUF = OFF_GX + 268435456;      // u32  8 grp x 2 buf x [8][512]
static constexpr size_t OFF_BAR  = OFF_HBUF + 262144;       // u32  8 x 64 (32 used/grp)
static constexpr size_t WS_NEED  = OFF_BAR + 4096;

// ---------------- K1: pack gate weights, transposed, to bf16 ----------------
__global__ __launch_bounds__(256) void pack_w(
    const float* __restrict__ s0, const float* __restrict__ s1,
    const float* __restrict__ s2, const float* __restrict__ s3,
    unsigned short* __restrict__ dst, int K) {
  __shared__ float tile[32][33];
  const int tx = threadIdx.x & 31, ty = threadIdx.x >> 5;
  const int kt = blockIdx.x, nt = blockIdx.y;
  const int q = (nt * 32) >> 10;
  const float* src = (q == 0) ? s0 : (q == 1) ? s1 : (q == 2) ? s2 : s3;
  const int cbase = (nt * 32) & 1023;
#pragma unroll
  for (int i = 0; i < 4; ++i) {
    int k = kt * 32 + ty + i * 8;
    tile[ty + i * 8][tx] = src[(size_t)k * 1024 + cbase + tx];
  }
  __syncthreads();
#pragma unroll
  for (int i = 0; i < 4; ++i) {
    int n = nt * 32 + ty + i * 8;
    dst[(size_t)n * K + kt * 32 + tx] = f2bf(tile[tx][ty + i * 8]);
  }
}

// ---------------- K2: combined bias bx+bh ----------------
__global__ __launch_bounds__(256) void pack_bias(
    const float* bx0, const float* bx1, const float* bx2, const float* bx3,
    const float* bh0, const float* bh1, const float* bh2, const float* bh3,
    float* __restrict__ bsum) {
  int n = blockIdx.x * 256 + threadIdx.x;
  int q = n >> 10, j = n & 1023;
  const float* bx = (q == 0) ? bx0 : (q == 1) ? bx1 : (q == 2) ? bx2 : bx3;
  const float* bh = (q == 0) ? bh0 : (q == 1) ? bh1 : (q == 2) ? bh2 : bh3;
  bsum[n] = bx[j] + bh[j];
}

// ---------------- K3: build xs bf16 [T*B][1600] ----------------
__global__ __launch_bounds__(256) void xs_pack(
    const float* __restrict__ x, const float* __restrict__ y,
    unsigned int* __restrict__ xs32) {
  __shared__ float xt[32][33], yt[32][33];
  const int tx = threadIdx.x & 31, ty = threadIdx.x >> 5;
  const int tt = blockIdx.x, ct = blockIdx.y, b = blockIdx.z;
#pragma unroll
  for (int i = 0; i < 4; ++i) {
    int c = ct * 32 + ty + i * 8;
    int t = tt * 32 + tx;
    size_t base = ((size_t)b * 800 + c) * 512;
    xt[ty + i * 8][tx] = x[base + t];
    yt[ty + i * 8][tx] = (t == 0) ? 0.f : y[base + t - 1];
  }
  __syncthreads();
#pragma unroll
  for (int i = 0; i < 4; ++i) {
    int t = tt * 32 + ty + i * 8;
    int c = ct * 32 + tx;
    unsigned int pk = ((unsigned int)f2bf(yt[tx][ty + i * 8]) << 16) |
                      (unsigned int)f2bf(xt[tx][ty + i * 8]);
    xs32[((size_t)t * 64 + b) * 800 + c] = pk;
  }
}

// ---------------- K4: gx GEMM (m97 structure) ----------------
// col = q*1024 + ghc  ->  colp = ghc*4 + q  (4 gates of an h-col adjacent)
__global__ __launch_bounds__(256, 2) void gemm_gx(
    const unsigned short* __restrict__ xs, const unsigned short* __restrict__ Wxt,
    const float* __restrict__ bsum, _Float16* __restrict__ gx) {
  __shared__ __align__(16) unsigned short Al[128 * 64];
  __shared__ __align__(16) unsigned short Bl[128 * 64];
  const int tid = threadIdx.x;
  const int w = tid >> 6, l = tid & 63;
  const int l15 = l & 15, l4 = l >> 4;
  const int wm = w >> 1, wn = w & 1;
  const int u = (blockIdx.x & 7) * 1024 + (blockIdx.x >> 3);
  const int bm = u >> 5, bn = u & 31;

  f32x4 acc[4][4];
#pragma unroll
  for (int i = 0; i < 4; ++i)
#pragma unroll
    for (int j = 0; j < 4; ++j) acc[i][j] = (f32x4){0.f, 0.f, 0.f, 0.f};

  const int srow = w * 8 + (l >> 3);
  const int scol = (l & 7) * 8;

  for (int kt = 0; kt < 25; ++kt) {
#pragma unroll
    for (int rnd = 0; rnd < 4; ++rnd) {
      int row = rnd * 32 + srow;
      gload_lds16(xs + ((size_t)(bm * 128 + row)) * 1600 + kt * 64 + scol,
                  Al + rnd * 2048 + w * 512);
      gload_lds16(Wxt + ((size_t)(bn * 128 + row)) * 1600 + kt * 64 + scol,
                  Bl + rnd * 2048 + w * 512);
    }
    __syncthreads();
#pragma unroll
    for (int kk = 0; kk < 64; kk += 32) {
      short8 av[4], bv[4];
#pragma unroll
      for (int mf = 0; mf < 4; ++mf)
        av[mf] = *(const short8*)&Al[(wm * 64 + mf * 16 + l15) * 64 + kk + l4 * 8];
#pragma unroll
      for (int nf = 0; nf < 4; ++nf)
        bv[nf] = *(const short8*)&Bl[(wn * 64 + nf * 16 + l15) * 64 + kk + l4 * 8];
#pragma unroll
      for (int mf = 0; mf < 4; ++mf)
#pragma unroll
        for (int nf = 0; nf < 4; ++nf)
          acc[mf][nf] = __builtin_amdgcn_mfma_f32_16x16x32_bf16(
              av[mf], bv[nf], acc[mf][nf], 0, 0, 0);
    }
    __syncthreads();
  }
#pragma unroll
  for (int nf = 0; nf < 4; ++nf) {
    int col = bn * 128 + wn * 64 + nf * 16 + l15;
    float bs = bsum[col];
    int colp = (col & 1023) * 4 + (col >> 10);
#pragma unroll
    for (int mf = 0; mf < 4; ++mf) {
      int row0 = bm * 128 + wm * 64 + mf * 16 + l4 * 4;
#pragma unroll
      for (int j = 0; j < 4; ++j)
        gx[(size_t)(row0 + j) * 4096 + colp] = (_Float16)(acc[mf][nf][j] + bs);
    }
  }
}

// ---------------- K5: persistent LSTM recurrence (barrier-free step loop) ----
// 8 groups (gg=blockIdx&7) x 32 WGs (cwg), 512 thr, 96KB LDS -> 1 WG/CU.
// Wave w: ws=w&1, kq=w>>1. No __syncthreads in the step loop; intra-WG sync
// via LDS seq-flags lf[]: 0=detect, 1..4=stage[kq], 5..10=part[(ws*3)+kq-1],
// 11=fin(ws1). Global protocol is R3-exact: wave7 relay-polls 32 gflag slots,
// single gflag store by wave0 lane0 after BOTH finalizer waves drained.
// Step: w7 poll->lf0 -> stagers (ws=0) load own 4KB K-slice (LLC) -> swizzled
// ds_write -> lf[1+kq] -> all waves 32 MFMAs -> kq>0: partials+lf -> kq=0:
// spin 3 partflags, reduce+gates+h-store+drain; w1->lf11; w0 waits lf11,
// stores gflag. Bounded spins everywhere.
__global__ __launch_bounds__(512, 2) void lstm_seq(
    const _Float16* __restrict__ gx, const unsigned short* __restrict__ Wht,
    const float* __restrict__ subj, const float* __restrict__ Winit,
    const float* __restrict__ binit, float* __restrict__ out,
    unsigned int* __restrict__ hbuf, unsigned int* __restrict__ bar) {
  const int gg  = blockIdx.x & 7;
  const int cwg = blockIdx.x >> 3;
  const int tid = threadIdx.x;
  const int w = tid >> 6, l = tid & 63;
  const int l15 = l & 15, l4 = l >> 4;
  const int ws = w & 1, kq = w >> 1;
  const int ghc = cwg * 32 + ws * 16 + l15;  // this lane's h-col (B operand)

  __shared__ __align__(16) char smem[98304];  // 96 KB -> exclusive CU
  volatile unsigned* lf = (volatile unsigned*)(smem + 40960);  // seq-flags [16]
  if (tid < 16) lf[tid] = 0;

  // Wh B-fragments (128 VGPR), resident across all 512 steps
  short8 Bf[32];
  {
    const unsigned short* wp = Wht + (size_t)ghc * 1024 + kq * 256 + l4 * 8;
#pragma unroll
    for (int g = 0; g < 4; ++g)
#pragma unroll
      for (int ks = 0; ks < 8; ++ks)
        Bf[g * 8 + ks] = *(const short8*)(wp + (size_t)g * 1048576 + ks * 32);
  }

  // c0 = subject_id @ W_init + b_init (finalizer lanes only)
  float c[4], hq[4][4];
  if (w < 2 && l4 < 2) {
#pragma unroll
    for (int j = 0; j < 4; ++j) {
      int b = gg * 8 + l4 * 4 + j;
      float a = binit[ghc];
      for (int k = 0; k < 87; ++k) a += subj[b * 87 + k] * Winit[k * 1024 + ghc];
      c[j] = a;
    }
  }

  unsigned int* gflags = bar + gg * 64;  // 32 slots used (one per WG)

  __syncthreads();  // one-time: lf zeros visible

  // stager addressing: lane l covers row l>>3, bytes (l&7)*64..+64 of K-slice
  const int srow = l >> 3;
  const int scol = (l & 7) * 64;

  for (int t4 = 0; t4 < 128; ++t4) {
#pragma unroll
    for (int s = 0; s < 4; ++s) {
      const int t = t4 * 4 + s;
      const int cur = t & 1;
      const unsigned stepv = (unsigned)(t + 1);
      // 1. wave7: global relay poll (R3-exact), then LDS detect flag
      if (w == 7) {
        const unsigned tgt = (unsigned)t;
        for (int spin = 0; spin < (1 << 20); ++spin) {
          unsigned f = 0xFFFFFFFFu;
          if (l < 32) f = flag_load(gflags + l);
          if (__all(f >= tgt)) break;
          __builtin_amdgcn_s_sleep(2);
        }
        if (l == 0) lf[0] = stepv;
      }
      f16x4 gxq[4];
      if (ws == 0) {
        // 2a. stagers: wait detect, stage own K-slice, flag, fall into MFMA
        if (w != 0 || l == 0 || true) lds_spin(lf + 0, stepv);
        const char* src = (const char*)hbuf + (size_t)(gg * 2 + cur) * 16384 +
                          srow * 2048 + kq * 512 + scol;
        u32x4 v0 = h_load16(src);
        u32x4 v1 = h_load16(src + 16);
        u32x4 v2 = h_load16(src + 32);
        u32x4 v3 = h_load16(src + 48);
        if (w == 0 && l4 < 2) {  // wave0 finalizer: gx loads ride with stage
          const _Float16* gp =
              gx + ((size_t)(t * 64 + gg * 8 + l4 * 4)) * 4096 + ghc * 4;
#pragma unroll
          for (int j = 0; j < 4; ++j) gxq[j] = *(const f16x4*)(gp + (size_t)j * 4096);
        }
        asm volatile("s_waitcnt vmcnt(0)" ::: "memory");
        {
          int b0 = srow * 2048 + kq * 512 + scol;
          int sw = (srow & 7) << 4;
          *(u32x4*)(smem + ((b0) ^ sw)) = v0;
          *(u32x4*)(smem + ((b0 + 16) ^ sw)) = v1;
          *(u32x4*)(smem + ((b0 + 32) ^ sw)) = v2;
          *(u32x4*)(smem + ((b0 + 48) ^ sw)) = v3;
        }
        asm volatile("s_waitcnt lgkmcnt(0)" ::: "memory");
        __builtin_amdgcn_sched_barrier(0);
        if (l == 0) lf[1 + kq] = stepv;
      } else {
        // 2b. consumers: wait own slice staged
        lds_spin(lf + 1 + kq, stepv);
        if (w == 1 && l4 < 2) {  // wave1 finalizer: gx loads
          const _Float16* gp =
              gx + ((size_t)(t * 64 + gg * 8 + l4 * 4)) * 4096 + ghc * 4;
#pragma unroll
          for (int j = 0; j < 4; ++j) gxq[j] = *(const f16x4*)(gp + (size_t)j * 4096);
        }
      }
      // 3. MFMA: 8 A-reads (K-slice kq), each feeds 4 gate-MFMAs
      f32x4 acc[4];
#pragma unroll
      for (int g = 0; g < 4; ++g) acc[g] = (f32x4){0.f, 0.f, 0.f, 0.f};
#pragma unroll
      for (int ks = 0; ks < 8; ++ks) {
        short8 a = *(const short8*)(
            smem + (((l15 & 7) * 2048 + kq * 512 + ks * 64 + l4 * 16) ^ ((l15 & 7) << 4)));
#pragma unroll
        for (int g = 0; g < 4; ++g)
          acc[g] = __builtin_amdgcn_mfma_f32_16x16x32_bf16(a, Bf[g * 8 + ks], acc[g], 0, 0, 0);
      }
      if (w >= 2) {
        // 4. producers: partials + flag
        char* pb = smem + 16384 + (size_t)(ws * 3 + kq - 1) * 4096;
#pragma unroll
        for (int g = 0; g < 4; ++g) *(f32x4*)(pb + g * 1024 + l * 16) = acc[g];
        asm volatile("s_waitcnt lgkmcnt(0)" ::: "memory");
        if (l == 0) lf[5 + ws * 3 + kq - 1] = stepv;
      } else {
        // 5. finalizers: wait 3 partflags, reduce, gates, store, drain
        {
          volatile unsigned* p0 = lf + 5 + ws * 3;
          for (int i = 0; i < (1 << 22); ++i) {
            if (p0[0] >= stepv && p0[1] >= stepv && p0[2] >= stepv) break;
          }
          asm volatile("" ::: "memory");
          __builtin_amdgcn_sched_barrier(0);
        }
        f32x4 red[4];
#pragma unroll
        for (int g = 0; g < 4; ++g) {
          red[g] = acc[g];
#pragma unroll
          for (int kk = 0; kk < 3; ++kk)
            red[g] += *(const f32x4*)(smem + 16384 + (size_t)(ws * 3 + kk) * 4096 +
                                      g * 1024 + l * 16);
        }
        if (l4 < 2) {
#pragma unroll
          for (int j = 0; j < 4; ++j) {
            float fv = sigm(red[0][j] + (float)gxq[j][0]);
            float iv = sigm(red[1][j] + (float)gxq[j][1]);
            float uv = tanh_(red[2][j] + (float)gxq[j][2]);
            float ov = sigm(red[3][j] + (float)gxq[j][3]);
            c[j] = c[j] * fv + iv * uv;
            float hv = ov * tanh_(c[j]);
            hq[j][s] = hv;
            float hn = __shfl_xor(hv, 1);  // neighbor h-col for u32 packing
            if (!(l15 & 1)) {
              unsigned int pk = (unsigned int)f2bf(hv) | ((unsigned int)f2bf(hn) << 16);
              h_store4(hbuf + (size_t)(gg * 2 + (cur ^ 1)) * 4096 +
                           (l4 * 4 + j) * 512 + cwg * 16 + ws * 8 + (l15 >> 1),
                       pk);
            }
          }
        }
        asm volatile("s_waitcnt vmcnt(0)" ::: "memory");  // own h-stores at LLC
        if (ws == 1) {
          if (l == 0) lf[11] = stepv;          // wave1 drained
        } else {
          lds_spin(lf + 11, stepv);            // wave0: wait wave1
          if (l == 0) h_store4(gflags + cwg, stepv);  // single gflag (R3-exact)
        }
      }
    }
    // flush 4-step h_seq window (16B per lane per row)
    if (w < 2 && l4 < 2) {
      int tb = t4 * 4;
#pragma unroll
      for (int j = 0; j < 4; ++j) {
        f32x4 v = {hq[j][0], hq[j][1], hq[j][2], hq[j][3]};
        *(f32x4*)(out + (size_t)(gg * 8 + l4 * 4 + j) * 524288 + (size_t)ghc * 512 + tb) = v;
      }
    }
  }
  if (w < 2 && l4 < 2) {  // c_fin
#pragma unroll
    for (int j = 0; j < 4; ++j)
      out[33554432 + (size_t)(gg * 8 + l4 * 4 + j) * 1024 + ghc] = c[j];
  }
}

// ---------------- launch ----------------
extern "C" void kernel_launch(void* const* d_in, const int* in_sizes, int n_in,
                              void* d_out, int out_size, void* d_ws, size_t ws_size,
                              hipStream_t stream) {
  (void)in_sizes; (void)n_in; (void)out_size;
  if (ws_size < WS_NEED) return;

  const float* x     = (const float*)d_in[0];
  const float* y     = (const float*)d_in[1];
  const float* subj  = (const float*)d_in[2];
  const float* W_fx  = (const float*)d_in[3];
  const float* b_fx  = (const float*)d_in[4];
  const float* W_fh  = (const float*)d_in[5];
  const float* b_fh  = (const float*)d_in[6];
  const float* W_ix  = (const float*)d_in[7];
  const float* b_ix  = (const float*)d_in[8];
  const float* W_ih  = (const float*)d_in[9];
  const float* b_ih  = (const float*)d_in[10];
  const float* W_ux  = (const float*)d_in[11];
  const float* b_ux  = (const float*)d_in[12];
  const float* W_uh  = (const float*)d_in[13];
  const float* b_uh  = (const float*)d_in[14];
  const float* W_ox  = (const float*)d_in[15];
  const float* b_ox  = (const float*)d_in[16];
  const float* W_oh  = (const float*)d_in[17];
  const float* b_oh  = (const float*)d_in[18];
  const float* Winit = (const float*)d_in[19];
  const float* binit = (const float*)d_in[20];
  float* out = (float*)d_out;

  char* ws = (char*)d_ws;
  unsigned short* Wxt  = (unsigned short*)(ws + OFF_WXT);
  unsigned short* Wht  = (unsigned short*)(ws + OFF_WHT);
  float*          bsum = (float*)(ws + OFF_BSUM);
  unsigned int*   xs32 = (unsigned int*)(ws + OFF_XS);
  _Float16*       gx   = (_Float16*)(ws + OFF_GX);
  unsigned int*   hbuf = (unsigned int*)(ws + OFF_HBUF);
  unsigned int*   bar  = (unsigned int*)(ws + OFF_BAR);

  // deterministic per-call init: h(0)=0 in both buffers, flags=0
  hipMemsetAsync(ws + OFF_HBUF, 0, WS_NEED - OFF_HBUF, stream);

  pack_w<<<dim3(50, 128), 256, 0, stream>>>(W_fx, W_ix, W_ux, W_ox, Wxt, 1600);
  pack_w<<<dim3(32, 128), 256, 0, stream>>>(W_fh, W_ih, W_uh, W_oh, Wht, 1024);
  pack_bias<<<16, 256, 0, stream>>>(b_fx, b_ix, b_ux, b_ox, b_fh, b_ih, b_uh, b_oh, bsum);
  xs_pack<<<dim3(16, 25, 64), 256, 0, stream>>>(x, y, xs32);
  gemm_gx<<<8192, 256, 0, stream>>>((const unsigned short*)xs32, Wxt, bsum, gx);

  const _Float16* gxc = gx;
  const unsigned short* whtc = Wht;
  void* ka[8] = {(void*)&gxc, (void*)&whtc, (void*)&subj, (void*)&Winit,
                 (void*)&binit, (void*)&out, (void*)&hbuf, (void*)&bar};
  hipError_t e = hipLaunchCooperativeKernel((const void*)lstm_seq, dim3(256), dim3(512),
                                            ka, 0, stream);
  if (e != hipSuccess) {
    // fallback: plain launch; 256 WGs at 1 WG/CU (96KB LDS) co-resident on 256 CUs
    lstm_seq<<<256, 512, 0, stream>>>(gxc, whtc, subj, Winit, binit, out, hbuf, bar);
  }
}

// Round 12
// 2788.903 us; speedup vs baseline: 1.7113x; 1.7113x over previous
//
#include <hip/hip_runtime.h>

typedef __attribute__((ext_vector_type(8))) short short8;
typedef __attribute__((ext_vector_type(4))) float f32x4;
typedef __attribute__((ext_vector_type(4))) _Float16 f16x4;
typedef __attribute__((ext_vector_type(4))) unsigned int u32x4;
typedef unsigned long long u64_t;

#define DI __device__ __forceinline__

// ---------------- helpers ----------------
DI unsigned short f2bf(float f) {            // RNE float->bf16
  unsigned int u = __float_as_uint(f);
  u += 0x7FFFu + ((u >> 16) & 1u);
  return (unsigned short)(u >> 16);
}

DI void gload_lds16(const void* g, void* l) { // async global->LDS, 16B/lane
  __builtin_amdgcn_global_load_lds(
      (const __attribute__((address_space(1))) unsigned int*)g,
      (__attribute__((address_space(3))) unsigned int*)l, 16, 0, 0);
}

DI float sigm(float x) { return 1.f / (1.f + __expf(-x)); }
DI float tanh_(float x) { return 1.f - 2.f / (__expf(2.f * x) + 1.f); }

// LLC-coherent 16B load (sc0 sc1) — correctness-proven in the R10 stage role
DI u32x4 h_load16(const void* p) {  // no waitcnt: caller drains once
  u32x4 r;
  asm volatile("global_load_dwordx4 %0, %1, off sc0 sc1" : "=v"(r) : "v"(p) : "memory");
  return r;
}

// ---------------- sizes / workspace layout ----------------
// B=64 C=800 T=512 H=1024 IN=1600 4H=4096 TB=32768
static constexpr size_t OFF_WXT  = 0;                       // bf16 [4096][1600]
static constexpr size_t OFF_WHT  = 13107200;                // bf16 [4096][1024]
static constexpr size_t OFF_BSUM = OFF_WHT + 8388608;       // f32  [4096] (bx+bh)
static constexpr size_t OFF_XS   = OFF_BSUM + 16384;        // u32  [32768][800] (bf16 x,y interleaved)
static constexpr size_t OFF_GX   = OFF_XS + 104857600;      // f16  [32768][4096] (col-permuted)
static constexpr size_t OFF_HBUF = OFF_GX + 268435456;      // u32  8 grp x 2 buf x [8][512]
static constexpr size_t OFF_BAR  = OFF_HBUF + 262144;       // u32  8 x 32 arrival flags
static constexpr size_t WS_NEED  = OFF_BAR + 2048;

// ---------------- K1: pack gate weights, transposed, to bf16 ----------------
__global__ __launch_bounds__(256) void pack_w(
    const float* __restrict__ s0, const float* __restrict__ s1,
    const float* __restrict__ s2, const float* __restrict__ s3,
    unsigned short* __restrict__ dst, int K) {
  __shared__ float tile[32][33];
  const int tx = threadIdx.x & 31, ty = threadIdx.x >> 5;
  const int kt = blockIdx.x, nt = blockIdx.y;
  const int q = (nt * 32) >> 10;
  const float* src = (q == 0) ? s0 : (q == 1) ? s1 : (q == 2) ? s2 : s3;
  const int cbase = (nt * 32) & 1023;
#pragma unroll
  for (int i = 0; i < 4; ++i) {
    int k = kt * 32 + ty + i * 8;
    tile[ty + i * 8][tx] = src[(size_t)k * 1024 + cbase + tx];
  }
  __syncthreads();
#pragma unroll
  for (int i = 0; i < 4; ++i) {
    int n = nt * 32 + ty + i * 8;
    dst[(size_t)n * K + kt * 32 + tx] = f2bf(tile[tx][ty + i * 8]);
  }
}

// ---------------- K2: combined bias bx+bh ----------------
__global__ __launch_bounds__(256) void pack_bias(
    const float* bx0, const float* bx1, const float* bx2, const float* bx3,
    const float* bh0, const float* bh1, const float* bh2, const float* bh3,
    float* __restrict__ bsum) {
  int n = blockIdx.x * 256 + threadIdx.x;
  int q = n >> 10, j = n & 1023;
  const float* bx = (q == 0) ? bx0 : (q == 1) ? bx1 : (q == 2) ? bx2 : bx3;
  const float* bh = (q == 0) ? bh0 : (q == 1) ? bh1 : (q == 2) ? bh2 : bh3;
  bsum[n] = bx[j] + bh[j];
}

// ---------------- K3: build xs bf16 [T*B][1600] ----------------
__global__ __launch_bounds__(256) void xs_pack(
    const float* __restrict__ x, const float* __restrict__ y,
    unsigned int* __restrict__ xs32) {
  __shared__ float xt[32][33], yt[32][33];
  const int tx = threadIdx.x & 31, ty = threadIdx.x >> 5;
  const int tt = blockIdx.x, ct = blockIdx.y, b = blockIdx.z;
#pragma unroll
  for (int i = 0; i < 4; ++i) {
    int c = ct * 32 + ty + i * 8;
    int t = tt * 32 + tx;
    size_t base = ((size_t)b * 800 + c) * 512;
    xt[ty + i * 8][tx] = x[base + t];
    yt[ty + i * 8][tx] = (t == 0) ? 0.f : y[base + t - 1];
  }
  __syncthreads();
#pragma unroll
  for (int i = 0; i < 4; ++i) {
    int t = tt * 32 + ty + i * 8;
    int c = ct * 32 + tx;
    unsigned int pk = ((unsigned int)f2bf(yt[tx][ty + i * 8]) << 16) |
                      (unsigned int)f2bf(xt[tx][ty + i * 8]);
    xs32[((size_t)t * 64 + b) * 800 + c] = pk;
  }
}

// ---------------- K4: gx GEMM (m97 structure) ----------------
// col = q*1024 + ghc  ->  colp = ghc*4 + q  (4 gates of an h-col adjacent)
__global__ __launch_bounds__(256, 2) void gemm_gx(
    const unsigned short* __restrict__ xs, const unsigned short* __restrict__ Wxt,
    const float* __restrict__ bsum, _Float16* __restrict__ gx) {
  __shared__ __align__(16) unsigned short Al[128 * 64];
  __shared__ __align__(16) unsigned short Bl[128 * 64];
  const int tid = threadIdx.x;
  const int w = tid >> 6, l = tid & 63;
  const int l15 = l & 15, l4 = l >> 4;
  const int wm = w >> 1, wn = w & 1;
  const int u = (blockIdx.x & 7) * 1024 + (blockIdx.x >> 3);
  const int bm = u >> 5, bn = u & 31;

  f32x4 acc[4][4];
#pragma unroll
  for (int i = 0; i < 4; ++i)
#pragma unroll
    for (int j = 0; j < 4; ++j) acc[i][j] = (f32x4){0.f, 0.f, 0.f, 0.f};

  const int srow = w * 8 + (l >> 3);
  const int scol = (l & 7) * 8;

  for (int kt = 0; kt < 25; ++kt) {
#pragma unroll
    for (int rnd = 0; rnd < 4; ++rnd) {
      int row = rnd * 32 + srow;
      gload_lds16(xs + ((size_t)(bm * 128 + row)) * 1600 + kt * 64 + scol,
                  Al + rnd * 2048 + w * 512);
      gload_lds16(Wxt + ((size_t)(bn * 128 + row)) * 1600 + kt * 64 + scol,
                  Bl + rnd * 2048 + w * 512);
    }
    __syncthreads();
#pragma unroll
    for (int kk = 0; kk < 64; kk += 32) {
      short8 av[4], bv[4];
#pragma unroll
      for (int mf = 0; mf < 4; ++mf)
        av[mf] = *(const short8*)&Al[(wm * 64 + mf * 16 + l15) * 64 + kk + l4 * 8];
#pragma unroll
      for (int nf = 0; nf < 4; ++nf)
        bv[nf] = *(const short8*)&Bl[(wn * 64 + nf * 16 + l15) * 64 + kk + l4 * 8];
#pragma unroll
      for (int mf = 0; mf < 4; ++mf)
#pragma unroll
        for (int nf = 0; nf < 4; ++nf)
          acc[mf][nf] = __builtin_amdgcn_mfma_f32_16x16x32_bf16(
              av[mf], bv[nf], acc[mf][nf], 0, 0, 0);
    }
    __syncthreads();
  }
#pragma unroll
  for (int nf = 0; nf < 4; ++nf) {
    int col = bn * 128 + wn * 64 + nf * 16 + l15;
    float bs = bsum[col];
    int colp = (col & 1023) * 4 + (col >> 10);
#pragma unroll
    for (int mf = 0; mf < 4; ++mf) {
      int row0 = bm * 128 + wm * 64 + mf * 16 + l4 * 4;
#pragma unroll
      for (int j = 0; j < 4; ++j)
        gx[(size_t)(row0 + j) * 4096 + colp] = (_Float16)(acc[mf][nf][j] + bs);
    }
  }
}

// ---------------- K5: persistent LSTM recurrence (R3 protocol, batched stage)
// 8 groups (gg=blockIdx&7) x 32 WGs (cwg), 512 thr, 96KB LDS -> 1 WG/CU.
// Wave w: ws=w&1 (h-col half), kq=w>>1 (K-slice of 256). Per step:
//   wave7 relay-polls the 32 per-WG flags -> syncA ->
//   cooperative 16KB h stage: 2 x dwordx4 sc0sc1 / thread, ONE vmcnt(0),
//   2 swizzled 16B ds_writes (same byte permutation as R3) ->
//   gx loads (finalizer lanes) -> syncB -> 32 MFMAs (kq K-split x 4-gate A
//   reuse) -> partials to LDS -> syncC -> finalizers (kq=0) reduce + gates +
//   h-store -> vmcnt(0) -> syncD -> tid0 stores single per-WG flag.
__global__ __launch_bounds__(512, 2) void lstm_seq(
    const _Float16* __restrict__ gx, const unsigned short* __restrict__ Wht,
    const float* __restrict__ subj, const float* __restrict__ Winit,
    const float* __restrict__ binit, float* __restrict__ out,
    unsigned int* __restrict__ hbuf, unsigned int* __restrict__ bar) {
  const int gg  = blockIdx.x & 7;
  const int cwg = blockIdx.x >> 3;
  const int tid = threadIdx.x;
  const int w = tid >> 6, l = tid & 63;
  const int l15 = l & 15, l4 = l >> 4;
  const int ws = w & 1, kq = w >> 1;
  const int ghc = cwg * 32 + ws * 16 + l15;  // this lane's h-col (B operand)

  __shared__ __align__(16) char smem[98304];  // 96 KB -> exclusive CU

  // Wh B-fragments (128 VGPR), resident across all 512 steps
  short8 Bf[32];
  {
    const unsigned short* wp =
        Wht + (size_t)(cwg * 32 + ws * 16 + l15) * 1024 + kq * 256 + l4 * 8;
#pragma unroll
    for (int g = 0; g < 4; ++g)
#pragma unroll
      for (int ks = 0; ks < 8; ++ks)
        Bf[g * 8 + ks] = *(const short8*)(wp + (size_t)g * 1048576 + ks * 32);
  }

  // c0 = subject_id @ W_init + b_init (finalizer lanes only)
  float c[4], hq[4][8];
  if (w < 2 && l4 < 2) {
#pragma unroll
    for (int j = 0; j < 4; ++j) {
      int b = gg * 8 + l4 * 4 + j;
      float a = binit[ghc];
      for (int k = 0; k < 87; ++k) a += subj[b * 87 + k] * Winit[k * 1024 + ghc];
      c[j] = a;
    }
  }

  unsigned int* flags = bar + gg * 32;

  // batched stage addressing: 16B chunks tid and tid+512 (1024 total = 16KB)
  const int so0 = tid * 16;
  const int so1 = (tid + 512) * 16;
  const int sw0 = so0 ^ (((so0 >> 11) & 7) << 4);
  const int sw1 = so1 ^ (((so1 >> 11) & 7) << 4);

  for (int t8 = 0; t8 < 64; ++t8) {
#pragma unroll
    for (int s = 0; s < 8; ++s) {
      const int t = t8 * 8 + s;
      const int cur = s & 1, nxt = cur ^ 1;
      // 1. poll: wave 7's 32 lanes read the 32 WG flags, ballot
      if (w == 7) {
        const unsigned tgt = (unsigned)t;
        for (;;) {
          unsigned f = 0xFFFFFFFFu;
          if (l < 32)
            f = __hip_atomic_load(flags + l, __ATOMIC_RELAXED, __HIP_MEMORY_SCOPE_AGENT);
          if (__all(f >= tgt)) break;
          __builtin_amdgcn_s_sleep(2);
        }
      }
      __syncthreads();  // A: h(t) visible to all
      // 2. batched cooperative stage: 2 x 16B loads, one drain, swizzled writes
      {
        const char* src = (const char*)hbuf + (size_t)(gg * 2 + cur) * 16384;
        u32x4 v0 = h_load16(src + so0);
        u32x4 v1 = h_load16(src + so1);
        asm volatile("s_waitcnt vmcnt(0)" ::: "memory");
        *(u32x4*)(smem + sw0) = v0;
        *(u32x4*)(smem + sw1) = v1;
      }
      // 3. gx loads (finalizer lanes; consumed after sync C)
      f16x4 gxq[4];
      if (w < 2 && l4 < 2) {
        const _Float16* gp =
            gx + ((size_t)(t * 64 + gg * 8 + l4 * 4)) * 4096 + ghc * 4;
#pragma unroll
        for (int j = 0; j < 4; ++j) gxq[j] = *(const f16x4*)(gp + (size_t)j * 4096);
      }
      __syncthreads();  // B: staged h readable
      // 4. MFMA: 8 A-reads, each feeds 4 gate-MFMAs
      f32x4 acc[4];
#pragma unroll
      for (int g = 0; g < 4; ++g) acc[g] = (f32x4){0.f, 0.f, 0.f, 0.f};
#pragma unroll
      for (int ks = 0; ks < 8; ++ks) {
        short8 a = *(const short8*)(
            smem + (((l15 & 7) * 2048 + kq * 512 + ks * 64 + l4 * 16) ^ ((l15 & 7) << 4)));
#pragma unroll
        for (int g = 0; g < 4; ++g)
          acc[g] = __builtin_amdgcn_mfma_f32_16x16x32_bf16(a, Bf[g * 8 + ks], acc[g], 0, 0, 0);
      }
      // 5. K-partials to LDS (waves kq>0)
      if (w >= 2) {
        char* pb = smem + 16384 + (size_t)(ws * 3 + kq - 1) * 4096;
#pragma unroll
        for (int g = 0; g < 4; ++g) *(f32x4*)(pb + g * 1024 + l * 16) = acc[g];
      }
      __syncthreads();  // C: partials readable
      // 6. reduce + gates + h-store (finalizer waves kq=0)
      if (w < 2) {
        f32x4 red[4];
#pragma unroll
        for (int g = 0; g < 4; ++g) {
          red[g] = acc[g];
#pragma unroll
          for (int kk = 0; kk < 3; ++kk)
            red[g] += *(const f32x4*)(smem + 16384 + (size_t)(ws * 3 + kk) * 4096 +
                                      g * 1024 + l * 16);
        }
        if (l4 < 2) {
#pragma unroll
          for (int j = 0; j < 4; ++j) {
            float fv = sigm(red[0][j] + (float)gxq[j][0]);
            float iv = sigm(red[1][j] + (float)gxq[j][1]);
            float uv = tanh_(red[2][j] + (float)gxq[j][2]);
            float ov = sigm(red[3][j] + (float)gxq[j][3]);
            c[j] = c[j] * fv + iv * uv;
            float hv = ov * tanh_(c[j]);
            hq[j][s] = hv;
            float hn = __shfl_xor(hv, 1);  // neighbor h-col for u32 packing
            if (!(l15 & 1)) {
              unsigned int pk = (unsigned int)f2bf(hv) | ((unsigned int)f2bf(hn) << 16);
              __hip_atomic_store(
                  hbuf + (gg * 2 + nxt) * 4096 + (l4 * 4 + j) * 512 +
                      cwg * 16 + ws * 8 + (l15 >> 1),
                  pk, __ATOMIC_RELAXED, __HIP_MEMORY_SCOPE_AGENT);
            }
          }
        }
      }
      asm volatile("s_waitcnt vmcnt(0)" ::: "memory");  // drain h-stores
      __syncthreads();  // D: both finalizer waves drained
      if (tid == 0)
        __hip_atomic_store(bar + gg * 32 + cwg, (unsigned)(t + 1),
                           __ATOMIC_RELAXED, __HIP_MEMORY_SCOPE_AGENT);
    }
    // flush 8-step h_seq window (32B chunks per lane)
    if (w < 2 && l4 < 2) {
      int tb = t8 * 8;
#pragma unroll
      for (int j = 0; j < 4; ++j) {
        f32x4 v0 = {hq[j][0], hq[j][1], hq[j][2], hq[j][3]};
        f32x4 v1 = {hq[j][4], hq[j][5], hq[j][6], hq[j][7]};
        float* op = out + (size_t)(gg * 8 + l4 * 4 + j) * 524288 + (size_t)ghc * 512 + tb;
        *(f32x4*)op = v0;
        *(f32x4*)(op + 4) = v1;
      }
    }
  }
  if (w < 2 && l4 < 2) {  // c_fin
#pragma unroll
    for (int j = 0; j < 4; ++j)
      out[33554432 + (size_t)(gg * 8 + l4 * 4 + j) * 1024 + ghc] = c[j];
  }
}

// ---------------- launch ----------------
extern "C" void kernel_launch(void* const* d_in, const int* in_sizes, int n_in,
                              void* d_out, int out_size, void* d_ws, size_t ws_size,
                              hipStream_t stream) {
  (void)in_sizes; (void)n_in; (void)out_size;
  if (ws_size < WS_NEED) return;

  const float* x     = (const float*)d_in[0];
  const float* y     = (const float*)d_in[1];
  const float* subj  = (const float*)d_in[2];
  const float* W_fx  = (const float*)d_in[3];
  const float* b_fx  = (const float*)d_in[4];
  const float* W_fh  = (const float*)d_in[5];
  const float* b_fh  = (const float*)d_in[6];
  const float* W_ix  = (const float*)d_in[7];
  const float* b_ix  = (const float*)d_in[8];
  const float* W_ih  = (const float*)d_in[9];
  const float* b_ih  = (const float*)d_in[10];
  const float* W_ux  = (const float*)d_in[11];
  const float* b_ux  = (const float*)d_in[12];
  const float* W_uh  = (const float*)d_in[13];
  const float* b_uh  = (const float*)d_in[14];
  const float* W_ox  = (const float*)d_in[15];
  const float* b_ox  = (const float*)d_in[16];
  const float* W_oh  = (const float*)d_in[17];
  const float* b_oh  = (const float*)d_in[18];
  const float* Winit = (const float*)d_in[19];
  const float* binit = (const float*)d_in[20];
  float* out = (float*)d_out;

  char* ws = (char*)d_ws;
  unsigned short* Wxt  = (unsigned short*)(ws + OFF_WXT);
  unsigned short* Wht  = (unsigned short*)(ws + OFF_WHT);
  float*          bsum = (float*)(ws + OFF_BSUM);
  unsigned int*   xs32 = (unsigned int*)(ws + OFF_XS);
  _Float16*       gx   = (_Float16*)(ws + OFF_GX);
  unsigned int*   hbuf = (unsigned int*)(ws + OFF_HBUF);
  unsigned int*   bar  = (unsigned int*)(ws + OFF_BAR);

  // deterministic per-call init: h(0)=0 in both buffers, flags=0
  hipMemsetAsync(ws + OFF_HBUF, 0, WS_NEED - OFF_HBUF, stream);

  pack_w<<<dim3(50, 128), 256, 0, stream>>>(W_fx, W_ix, W_ux, W_ox, Wxt, 1600);
  pack_w<<<dim3(32, 128), 256, 0, stream>>>(W_fh, W_ih, W_uh, W_oh, Wht, 1024);
  pack_bias<<<16, 256, 0, stream>>>(b_fx, b_ix, b_ux, b_ox, b_fh, b_ih, b_uh, b_oh, bsum);
  xs_pack<<<dim3(16, 25, 64), 256, 0, stream>>>(x, y, xs32);
  gemm_gx<<<8192, 256, 0, stream>>>((const unsigned short*)xs32, Wxt, bsum, gx);

  const _Float16* gxc = gx;
  const unsigned short* whtc = Wht;
  void* ka[8] = {(void*)&gxc, (void*)&whtc, (void*)&subj, (void*)&Winit,
                 (void*)&binit, (void*)&out, (void*)&hbuf, (void*)&bar};
  hipError_t e = hipLaunchCooperativeKernel((const void*)lstm_seq, dim3(256), dim3(512),
                                            ka, 0, stream);
  if (e != hipSuccess) {
    // fallback: plain launch; 256 WGs at 1 WG/CU (96KB LDS) co-resident on 256 CUs
    lstm_seq<<<256, 512, 0, stream>>>(gxc, whtc, subj, Winit, binit, out, hbuf, bar);
  }
}

// Round 13
// 2785.694 us; speedup vs baseline: 1.7133x; 1.0012x over previous
//
#include <hip/hip_runtime.h>

typedef __attribute__((ext_vector_type(8))) short short8;
typedef __attribute__((ext_vector_type(4))) float f32x4;
typedef __attribute__((ext_vector_type(4))) _Float16 f16x4;
typedef __attribute__((ext_vector_type(4))) unsigned int u32x4;
typedef unsigned long long u64_t;

#define DI __device__ __forceinline__

// ---------------- helpers ----------------
DI unsigned short f2bf(float f) {            // RNE float->bf16
  unsigned int u = __float_as_uint(f);
  u += 0x7FFFu + ((u >> 16) & 1u);
  return (unsigned short)(u >> 16);
}

DI void gload_lds16(const void* g, void* l) { // async global->LDS, 16B/lane
  __builtin_amdgcn_global_load_lds(
      (const __attribute__((address_space(1))) unsigned int*)g,
      (__attribute__((address_space(3))) unsigned int*)l, 16, 0, 0);
}

DI float sigm(float x) { return 1.f / (1.f + __expf(-x)); }
DI float tanh_(float x) { return 1.f - 2.f / (__expf(2.f * x) + 1.f); }

// LLC-coherent 16B load (sc0 sc1) — correctness-proven in the R12 stage role
DI u32x4 h_load16(const void* p) {  // no waitcnt: caller drains once
  u32x4 r;
  asm volatile("global_load_dwordx4 %0, %1, off sc0 sc1" : "=v"(r) : "v"(p) : "memory");
  return r;
}

// ---------------- sizes / workspace layout ----------------
// B=64 C=800 T=512 H=1024 IN=1600 4H=4096 TB=32768
// bar: flag for WG cwg of group gg at bar[(gg*32+cwg)*32] — one 128B LLC line
// per WG (kills same-line serialization of 32 stores + 32 polls per line).
static constexpr size_t OFF_WXT  = 0;                       // bf16 [4096][1600]
static constexpr size_t OFF_WHT  = 13107200;                // bf16 [4096][1024]
static constexpr size_t OFF_BSUM = OFF_WHT + 8388608;       // f32  [4096] (bx+bh)
static constexpr size_t OFF_XS   = OFF_BSUM + 16384;        // u32  [32768][800] (bf16 x,y interleaved)
static constexpr size_t OFF_GX   = OFF_XS + 104857600;      // f16  [32768][4096] (col-permuted)
static constexpr size_t OFF_HBUF = OFF_GX + 268435456;      // u32  8 grp x 2 buf x [8][512]
static constexpr size_t OFF_BAR  = OFF_HBUF + 262144;       // u32  256 x 32-stride flags (32 KB)
static constexpr size_t WS_NEED  = OFF_BAR + 32768;

// ---------------- K1: pack gate weights, transposed, to bf16 ----------------
__global__ __launch_bounds__(256) void pack_w(
    const float* __restrict__ s0, const float* __restrict__ s1,
    const float* __restrict__ s2, const float* __restrict__ s3,
    unsigned short* __restrict__ dst, int K) {
  __shared__ float tile[32][33];
  const int tx = threadIdx.x & 31, ty = threadIdx.x >> 5;
  const int kt = blockIdx.x, nt = blockIdx.y;
  const int q = (nt * 32) >> 10;
  const float* src = (q == 0) ? s0 : (q == 1) ? s1 : (q == 2) ? s2 : s3;
  const int cbase = (nt * 32) & 1023;
#pragma unroll
  for (int i = 0; i < 4; ++i) {
    int k = kt * 32 + ty + i * 8;
    tile[ty + i * 8][tx] = src[(size_t)k * 1024 + cbase + tx];
  }
  __syncthreads();
#pragma unroll
  for (int i = 0; i < 4; ++i) {
    int n = nt * 32 + ty + i * 8;
    dst[(size_t)n * K + kt * 32 + tx] = f2bf(tile[tx][ty + i * 8]);
  }
}

// ---------------- K2: combined bias bx+bh ----------------
__global__ __launch_bounds__(256) void pack_bias(
    const float* bx0, const float* bx1, const float* bx2, const float* bx3,
    const float* bh0, const float* bh1, const float* bh2, const float* bh3,
    float* __restrict__ bsum) {
  int n = blockIdx.x * 256 + threadIdx.x;
  int q = n >> 10, j = n & 1023;
  const float* bx = (q == 0) ? bx0 : (q == 1) ? bx1 : (q == 2) ? bx2 : bx3;
  const float* bh = (q == 0) ? bh0 : (q == 1) ? bh1 : (q == 2) ? bh2 : bh3;
  bsum[n] = bx[j] + bh[j];
}

// ---------------- K3: build xs bf16 [T*B][1600] ----------------
__global__ __launch_bounds__(256) void xs_pack(
    const float* __restrict__ x, const float* __restrict__ y,
    unsigned int* __restrict__ xs32) {
  __shared__ float xt[32][33], yt[32][33];
  const int tx = threadIdx.x & 31, ty = threadIdx.x >> 5;
  const int tt = blockIdx.x, ct = blockIdx.y, b = blockIdx.z;
#pragma unroll
  for (int i = 0; i < 4; ++i) {
    int c = ct * 32 + ty + i * 8;
    int t = tt * 32 + tx;
    size_t base = ((size_t)b * 800 + c) * 512;
    xt[ty + i * 8][tx] = x[base + t];
    yt[ty + i * 8][tx] = (t == 0) ? 0.f : y[base + t - 1];
  }
  __syncthreads();
#pragma unroll
  for (int i = 0; i < 4; ++i) {
    int t = tt * 32 + ty + i * 8;
    int c = ct * 32 + tx;
    unsigned int pk = ((unsigned int)f2bf(yt[tx][ty + i * 8]) << 16) |
                      (unsigned int)f2bf(xt[tx][ty + i * 8]);
    xs32[((size_t)t * 64 + b) * 800 + c] = pk;
  }
}

// ---------------- K4: gx GEMM (m97 structure) ----------------
// col = q*1024 + ghc  ->  colp = ghc*4 + q  (4 gates of an h-col adjacent)
__global__ __launch_bounds__(256, 2) void gemm_gx(
    const unsigned short* __restrict__ xs, const unsigned short* __restrict__ Wxt,
    const float* __restrict__ bsum, _Float16* __restrict__ gx) {
  __shared__ __align__(16) unsigned short Al[128 * 64];
  __shared__ __align__(16) unsigned short Bl[128 * 64];
  const int tid = threadIdx.x;
  const int w = tid >> 6, l = tid & 63;
  const int l15 = l & 15, l4 = l >> 4;
  const int wm = w >> 1, wn = w & 1;
  const int u = (blockIdx.x & 7) * 1024 + (blockIdx.x >> 3);
  const int bm = u >> 5, bn = u & 31;

  f32x4 acc[4][4];
#pragma unroll
  for (int i = 0; i < 4; ++i)
#pragma unroll
    for (int j = 0; j < 4; ++j) acc[i][j] = (f32x4){0.f, 0.f, 0.f, 0.f};

  const int srow = w * 8 + (l >> 3);
  const int scol = (l & 7) * 8;

  for (int kt = 0; kt < 25; ++kt) {
#pragma unroll
    for (int rnd = 0; rnd < 4; ++rnd) {
      int row = rnd * 32 + srow;
      gload_lds16(xs + ((size_t)(bm * 128 + row)) * 1600 + kt * 64 + scol,
                  Al + rnd * 2048 + w * 512);
      gload_lds16(Wxt + ((size_t)(bn * 128 + row)) * 1600 + kt * 64 + scol,
                  Bl + rnd * 2048 + w * 512);
    }
    __syncthreads();
#pragma unroll
    for (int kk = 0; kk < 64; kk += 32) {
      short8 av[4], bv[4];
#pragma unroll
      for (int mf = 0; mf < 4; ++mf)
        av[mf] = *(const short8*)&Al[(wm * 64 + mf * 16 + l15) * 64 + kk + l4 * 8];
#pragma unroll
      for (int nf = 0; nf < 4; ++nf)
        bv[nf] = *(const short8*)&Bl[(wn * 64 + nf * 16 + l15) * 64 + kk + l4 * 8];
#pragma unroll
      for (int mf = 0; mf < 4; ++mf)
#pragma unroll
        for (int nf = 0; nf < 4; ++nf)
          acc[mf][nf] = __builtin_amdgcn_mfma_f32_16x16x32_bf16(
              av[mf], bv[nf], acc[mf][nf], 0, 0, 0);
    }
    __syncthreads();
  }
#pragma unroll
  for (int nf = 0; nf < 4; ++nf) {
    int col = bn * 128 + wn * 64 + nf * 16 + l15;
    float bs = bsum[col];
    int colp = (col & 1023) * 4 + (col >> 10);
#pragma unroll
    for (int mf = 0; mf < 4; ++mf) {
      int row0 = bm * 128 + wm * 64 + mf * 16 + l4 * 4;
#pragma unroll
      for (int j = 0; j < 4; ++j)
        gx[(size_t)(row0 + j) * 4096 + colp] = (_Float16)(acc[mf][nf][j] + bs);
    }
  }
}

// ---------------- K5: persistent LSTM recurrence (R12 + spread flags) -------
// 8 groups (gg=blockIdx&7) x 32 WGs (cwg), 512 thr, 96KB LDS -> 1 WG/CU.
// Wave w: ws=w&1 (h-col half), kq=w>>1 (K-slice of 256). Per step:
//   wave7 relay-polls the 32 per-WG flags (each on its OWN 128B line) ->
//   syncA -> batched cooperative 16KB h stage (2 x dwordx4 sc0sc1, one
//   vmcnt(0), 2 swizzled 16B ds_writes) -> gx loads (finalizer lanes) ->
//   syncB -> 32 MFMAs (kq K-split x 4-gate A reuse) -> partials to LDS ->
//   syncC -> finalizers (kq=0) reduce + gates + h-store -> vmcnt(0) ->
//   syncD -> tid0 stores single per-WG flag (own line).
__global__ __launch_bounds__(512, 2) void lstm_seq(
    const _Float16* __restrict__ gx, const unsigned short* __restrict__ Wht,
    const float* __restrict__ subj, const float* __restrict__ Winit,
    const float* __restrict__ binit, float* __restrict__ out,
    unsigned int* __restrict__ hbuf, unsigned int* __restrict__ bar) {
  const int gg  = blockIdx.x & 7;
  const int cwg = blockIdx.x >> 3;
  const int tid = threadIdx.x;
  const int w = tid >> 6, l = tid & 63;
  const int l15 = l & 15, l4 = l >> 4;
  const int ws = w & 1, kq = w >> 1;
  const int ghc = cwg * 32 + ws * 16 + l15;  // this lane's h-col (B operand)

  __shared__ __align__(16) char smem[98304];  // 96 KB -> exclusive CU

  // Wh B-fragments (128 VGPR), resident across all 512 steps
  short8 Bf[32];
  {
    const unsigned short* wp =
        Wht + (size_t)(cwg * 32 + ws * 16 + l15) * 1024 + kq * 256 + l4 * 8;
#pragma unroll
    for (int g = 0; g < 4; ++g)
#pragma unroll
      for (int ks = 0; ks < 8; ++ks)
        Bf[g * 8 + ks] = *(const short8*)(wp + (size_t)g * 1048576 + ks * 32);
  }

  // c0 = subject_id @ W_init + b_init (finalizer lanes only)
  float c[4], hq[4][8];
  if (w < 2 && l4 < 2) {
#pragma unroll
    for (int j = 0; j < 4; ++j) {
      int b = gg * 8 + l4 * 4 + j;
      float a = binit[ghc];
      for (int k = 0; k < 87; ++k) a += subj[b * 87 + k] * Winit[k * 1024 + ghc];
      c[j] = a;
    }
  }

  unsigned int* flags = bar + gg * 1024;  // 32 WGs x 32-u32 stride (128B/line)

  // batched stage addressing: 16B chunks tid and tid+512 (1024 total = 16KB)
  const int so0 = tid * 16;
  const int so1 = (tid + 512) * 16;
  const int sw0 = so0 ^ (((so0 >> 11) & 7) << 4);
  const int sw1 = so1 ^ (((so1 >> 11) & 7) << 4);

  for (int t8 = 0; t8 < 64; ++t8) {
#pragma unroll
    for (int s = 0; s < 8; ++s) {
      const int t = t8 * 8 + s;
      const int cur = s & 1, nxt = cur ^ 1;
      // 1. poll: wave 7's 32 lanes read the 32 WG flags (distinct lines)
      if (w == 7) {
        const unsigned tgt = (unsigned)t;
        for (;;) {
          unsigned f = 0xFFFFFFFFu;
          if (l < 32)
            f = __hip_atomic_load(flags + l * 32, __ATOMIC_RELAXED,
                                  __HIP_MEMORY_SCOPE_AGENT);
          if (__all(f >= tgt)) break;
          __builtin_amdgcn_s_sleep(1);
        }
      }
      __syncthreads();  // A: h(t) visible to all
      // 2. batched cooperative stage: 2 x 16B loads, one drain, swizzled writes
      {
        const char* src = (const char*)hbuf + (size_t)(gg * 2 + cur) * 16384;
        u32x4 v0 = h_load16(src + so0);
        u32x4 v1 = h_load16(src + so1);
        asm volatile("s_waitcnt vmcnt(0)" ::: "memory");
        *(u32x4*)(smem + sw0) = v0;
        *(u32x4*)(smem + sw1) = v1;
      }
      // 3. gx loads (finalizer lanes; consumed after sync C)
      f16x4 gxq[4];
      if (w < 2 && l4 < 2) {
        const _Float16* gp =
            gx + ((size_t)(t * 64 + gg * 8 + l4 * 4)) * 4096 + ghc * 4;
#pragma unroll
        for (int j = 0; j < 4; ++j) gxq[j] = *(const f16x4*)(gp + (size_t)j * 4096);
      }
      __syncthreads();  // B: staged h readable
      // 4. MFMA: 8 A-reads, each feeds 4 gate-MFMAs
      f32x4 acc[4];
#pragma unroll
      for (int g = 0; g < 4; ++g) acc[g] = (f32x4){0.f, 0.f, 0.f, 0.f};
#pragma unroll
      for (int ks = 0; ks < 8; ++ks) {
        short8 a = *(const short8*)(
            smem + (((l15 & 7) * 2048 + kq * 512 + ks * 64 + l4 * 16) ^ ((l15 & 7) << 4)));
#pragma unroll
        for (int g = 0; g < 4; ++g)
          acc[g] = __builtin_amdgcn_mfma_f32_16x16x32_bf16(a, Bf[g * 8 + ks], acc[g], 0, 0, 0);
      }
      // 5. K-partials to LDS (waves kq>0)
      if (w >= 2) {
        char* pb = smem + 16384 + (size_t)(ws * 3 + kq - 1) * 4096;
#pragma unroll
        for (int g = 0; g < 4; ++g) *(f32x4*)(pb + g * 1024 + l * 16) = acc[g];
      }
      __syncthreads();  // C: partials readable
      // 6. reduce + gates + h-store (finalizer waves kq=0)
      if (w < 2) {
        f32x4 red[4];
#pragma unroll
        for (int g = 0; g < 4; ++g) {
          red[g] = acc[g];
#pragma unroll
          for (int kk = 0; kk < 3; ++kk)
            red[g] += *(const f32x4*)(smem + 16384 + (size_t)(ws * 3 + kk) * 4096 +
                                      g * 1024 + l * 16);
        }
        if (l4 < 2) {
#pragma unroll
          for (int j = 0; j < 4; ++j) {
            float fv = sigm(red[0][j] + (float)gxq[j][0]);
            float iv = sigm(red[1][j] + (float)gxq[j][1]);
            float uv = tanh_(red[2][j] + (float)gxq[j][2]);
            float ov = sigm(red[3][j] + (float)gxq[j][3]);
            c[j] = c[j] * fv + iv * uv;
            float hv = ov * tanh_(c[j]);
            hq[j][s] = hv;
            float hn = __shfl_xor(hv, 1);  // neighbor h-col for u32 packing
            if (!(l15 & 1)) {
              unsigned int pk = (unsigned int)f2bf(hv) | ((unsigned int)f2bf(hn) << 16);
              __hip_atomic_store(
                  hbuf + (gg * 2 + nxt) * 4096 + (l4 * 4 + j) * 512 +
                      cwg * 16 + ws * 8 + (l15 >> 1),
                  pk, __ATOMIC_RELAXED, __HIP_MEMORY_SCOPE_AGENT);
            }
          }
        }
      }
      asm volatile("s_waitcnt vmcnt(0)" ::: "memory");  // drain h-stores
      __syncthreads();  // D: both finalizer waves drained
      if (tid == 0)
        __hip_atomic_store(flags + cwg * 32, (unsigned)(t + 1),
                           __ATOMIC_RELAXED, __HIP_MEMORY_SCOPE_AGENT);
    }
    // flush 8-step h_seq window (32B chunks per lane)
    if (w < 2 && l4 < 2) {
      int tb = t8 * 8;
#pragma unroll
      for (int j = 0; j < 4; ++j) {
        f32x4 v0 = {hq[j][0], hq[j][1], hq[j][2], hq[j][3]};
        f32x4 v1 = {hq[j][4], hq[j][5], hq[j][6], hq[j][7]};
        float* op = out + (size_t)(gg * 8 + l4 * 4 + j) * 524288 + (size_t)ghc * 512 + tb;
        *(f32x4*)op = v0;
        *(f32x4*)(op + 4) = v1;
      }
    }
  }
  if (w < 2 && l4 < 2) {  // c_fin
#pragma unroll
    for (int j = 0; j < 4; ++j)
      out[33554432 + (size_t)(gg * 8 + l4 * 4 + j) * 1024 + ghc] = c[j];
  }
}

// ---------------- launch ----------------
extern "C" void kernel_launch(void* const* d_in, const int* in_sizes, int n_in,
                              void* d_out, int out_size, void* d_ws, size_t ws_size,
                              hipStream_t stream) {
  (void)in_sizes; (void)n_in; (void)out_size;
  if (ws_size < WS_NEED) return;

  const float* x     = (const float*)d_in[0];
  const float* y     = (const float*)d_in[1];
  const float* subj  = (const float*)d_in[2];
  const float* W_fx  = (const float*)d_in[3];
  const float* b_fx  = (const float*)d_in[4];
  const float* W_fh  = (const float*)d_in[5];
  const float* b_fh  = (const float*)d_in[6];
  const float* W_ix  = (const float*)d_in[7];
  const float* b_ix  = (const float*)d_in[8];
  const float* W_ih  = (const float*)d_in[9];
  const float* b_ih  = (const float*)d_in[10];
  const float* W_ux  = (const float*)d_in[11];
  const float* b_ux  = (const float*)d_in[12];
  const float* W_uh  = (const float*)d_in[13];
  const float* b_uh  = (const float*)d_in[14];
  const float* W_ox  = (const float*)d_in[15];
  const float* b_ox  = (const float*)d_in[16];
  const float* W_oh  = (const float*)d_in[17];
  const float* b_oh  = (const float*)d_in[18];
  const float* Winit = (const float*)d_in[19];
  const float* binit = (const float*)d_in[20];
  float* out = (float*)d_out;

  char* ws = (char*)d_ws;
  unsigned short* Wxt  = (unsigned short*)(ws + OFF_WXT);
  unsigned short* Wht  = (unsigned short*)(ws + OFF_WHT);
  float*          bsum = (float*)(ws + OFF_BSUM);
  unsigned int*   xs32 = (unsigned int*)(ws + OFF_XS);
  _Float16*       gx   = (_Float16*)(ws + OFF_GX);
  unsigned int*   hbuf = (unsigned int*)(ws + OFF_HBUF);
  unsigned int*   bar  = (unsigned int*)(ws + OFF_BAR);

  // deterministic per-call init: h(0)=0 in both buffers, flags=0
  hipMemsetAsync(ws + OFF_HBUF, 0, WS_NEED - OFF_HBUF, stream);

  pack_w<<<dim3(50, 128), 256, 0, stream>>>(W_fx, W_ix, W_ux, W_ox, Wxt, 1600);
  pack_w<<<dim3(32, 128), 256, 0, stream>>>(W_fh, W_ih, W_uh, W_oh, Wht, 1024);
  pack_bias<<<16, 256, 0, stream>>>(b_fx, b_ix, b_ux, b_ox, b_fh, b_ih, b_uh, b_oh, bsum);
  xs_pack<<<dim3(16, 25, 64), 256, 0, stream>>>(x, y, xs32);
  gemm_gx<<<8192, 256, 0, stream>>>((const unsigned short*)xs32, Wxt, bsum, gx);

  const _Float16* gxc = gx;
  const unsigned short* whtc = Wht;
  void* ka[8] = {(void*)&gxc, (void*)&whtc, (void*)&subj, (void*)&Winit,
                 (void*)&binit, (void*)&out, (void*)&hbuf, (void*)&bar};
  hipError_t e = hipLaunchCooperativeKernel((const void*)lstm_seq, dim3(256), dim3(512),
                                            ka, 0, stream);
  if (e != hipSuccess) {
    // fallback: plain launch; 256 WGs at 1 WG/CU (96KB LDS) co-resident on 256 CUs
    lstm_seq<<<256, 512, 0, stream>>>(gxc, whtc, subj, Winit, binit, out, hbuf, bar);
  }
}

// Round 14
// 2704.318 us; speedup vs baseline: 1.7648x; 1.0301x over previous
//
#include <hip/hip_runtime.h>

typedef __attribute__((ext_vector_type(8))) short short8;
typedef __attribute__((ext_vector_type(4))) float f32x4;
typedef __attribute__((ext_vector_type(4))) _Float16 f16x4;
typedef __attribute__((ext_vector_type(4))) unsigned int u32x4;
typedef unsigned long long u64_t;

#define DI __device__ __forceinline__

// ---------------- helpers ----------------
DI unsigned short f2bf(float f) {            // RNE float->bf16
  unsigned int u = __float_as_uint(f);
  u += 0x7FFFu + ((u >> 16) & 1u);
  return (unsigned short)(u >> 16);
}

DI void gload_lds16(const void* g, void* l) { // async global->LDS, 16B/lane
  __builtin_amdgcn_global_load_lds(
      (const __attribute__((address_space(1))) unsigned int*)g,
      (__attribute__((address_space(3))) unsigned int*)l, 16, 0, 0);
}

DI float sigm(float x) { return 1.f / (1.f + __expf(-x)); }
DI float tanh_(float x) { return 1.f - 2.f / (__expf(2.f * x) + 1.f); }

// LLC-coherent 16B load (sc0 sc1) — correctness-proven in the R12 stage role
DI u32x4 h_load16(const void* p) {  // no waitcnt: caller drains once
  u32x4 r;
  asm volatile("global_load_dwordx4 %0, %1, off sc0 sc1" : "=v"(r) : "v"(p) : "memory");
  return r;
}

// ---------------- sizes / workspace layout ----------------
// B=64 C=800 T=512 H=1024 IN=1600 4H=4096 TB=32768
static constexpr size_t OFF_WXT  = 0;                       // bf16 [4096][1600]
static constexpr size_t OFF_WHT  = 13107200;                // bf16 [4096][1024]
static constexpr size_t OFF_BSUM = OFF_WHT + 8388608;       // f32  [4096] (bx+bh)
static constexpr size_t OFF_XS   = OFF_BSUM + 16384;        // u32  [32768][800] (bf16 x,y interleaved)
static constexpr size_t OFF_GX   = OFF_XS + 104857600;      // f16  [32768][4096] (col-permuted)
static constexpr size_t OFF_HBUF = OFF_GX + 268435456;      // u32  8 grp x 2 buf x [8][512]
static constexpr size_t OFF_BAR  = OFF_HBUF + 262144;       // u32  256 x 32-stride flags (32 KB)
static constexpr size_t WS_NEED  = OFF_BAR + 32768;

// ---------------- K1: pack gate weights, transposed, to bf16 ----------------
__global__ __launch_bounds__(256) void pack_w(
    const float* __restrict__ s0, const float* __restrict__ s1,
    const float* __restrict__ s2, const float* __restrict__ s3,
    unsigned short* __restrict__ dst, int K) {
  __shared__ float tile[32][33];
  const int tx = threadIdx.x & 31, ty = threadIdx.x >> 5;
  const int kt = blockIdx.x, nt = blockIdx.y;
  const int q = (nt * 32) >> 10;
  const float* src = (q == 0) ? s0 : (q == 1) ? s1 : (q == 2) ? s2 : s3;
  const int cbase = (nt * 32) & 1023;
#pragma unroll
  for (int i = 0; i < 4; ++i) {
    int k = kt * 32 + ty + i * 8;
    tile[ty + i * 8][tx] = src[(size_t)k * 1024 + cbase + tx];
  }
  __syncthreads();
#pragma unroll
  for (int i = 0; i < 4; ++i) {
    int n = nt * 32 + ty + i * 8;
    dst[(size_t)n * K + kt * 32 + tx] = f2bf(tile[tx][ty + i * 8]);
  }
}

// ---------------- K2: combined bias bx+bh ----------------
__global__ __launch_bounds__(256) void pack_bias(
    const float* bx0, const float* bx1, const float* bx2, const float* bx3,
    const float* bh0, const float* bh1, const float* bh2, const float* bh3,
    float* __restrict__ bsum) {
  int n = blockIdx.x * 256 + threadIdx.x;
  int q = n >> 10, j = n & 1023;
  const float* bx = (q == 0) ? bx0 : (q == 1) ? bx1 : (q == 2) ? bx2 : bx3;
  const float* bh = (q == 0) ? bh0 : (q == 1) ? bh1 : (q == 2) ? bh2 : bh3;
  bsum[n] = bx[j] + bh[j];
}

// ---------------- K3: build xs bf16 [T*B][1600] ----------------
__global__ __launch_bounds__(256) void xs_pack(
    const float* __restrict__ x, const float* __restrict__ y,
    unsigned int* __restrict__ xs32) {
  __shared__ float xt[32][33], yt[32][33];
  const int tx = threadIdx.x & 31, ty = threadIdx.x >> 5;
  const int tt = blockIdx.x, ct = blockIdx.y, b = blockIdx.z;
#pragma unroll
  for (int i = 0; i < 4; ++i) {
    int c = ct * 32 + ty + i * 8;
    int t = tt * 32 + tx;
    size_t base = ((size_t)b * 800 + c) * 512;
    xt[ty + i * 8][tx] = x[base + t];
    yt[ty + i * 8][tx] = (t == 0) ? 0.f : y[base + t - 1];
  }
  __syncthreads();
#pragma unroll
  for (int i = 0; i < 4; ++i) {
    int t = tt * 32 + ty + i * 8;
    int c = ct * 32 + tx;
    unsigned int pk = ((unsigned int)f2bf(yt[tx][ty + i * 8]) << 16) |
                      (unsigned int)f2bf(xt[tx][ty + i * 8]);
    xs32[((size_t)t * 64 + b) * 800 + c] = pk;
  }
}

// ---------------- K4: gx GEMM — 256x256 tile, BK=32, 3-slot pipeline --------
// C[r][colp] = xs[r][:] . Wxt[col][:] + bsum[col], f16 out, colp = (col&1023)*4
// + (col>>10). 8 waves (2M x 4N), per-wave 128x64 out (acc[8][4] f32x4).
// LDS: 3 slots x (A 16KB + B 16KB) = 96KB, [256 rows][32 k] bf16 linear (64B
// rows -> frag reads are bank-pigeonhole-optimal, no swizzle needed).
// Pipeline: stage(t) issued 3 tiles ahead; raw s_barrier + counted vmcnt(8)
// (never 0 in steady state) -> no queue drain at barriers (the m97 stall).
__global__ __launch_bounds__(512, 2) void gemm_gx(
    const unsigned short* __restrict__ xs, const unsigned short* __restrict__ Wxt,
    const float* __restrict__ bsum, _Float16* __restrict__ gx) {
  __shared__ __align__(16) char smem[98304];  // A: 3x16KB @0, B: 3x16KB @49152
  const int tid = threadIdx.x;
  const int w = tid >> 6, l = tid & 63;
  const int l15 = l & 15, l4 = l >> 4;
  const int wm = w >> 2, wn = w & 3;
  // XCD-aware bijective swizzle (2048 % 8 == 0)
  const int u = (blockIdx.x & 7) * 256 + (blockIdx.x >> 3);
  const int bm = u >> 4, bn = u & 15;

  const unsigned short* abase0 = xs + (size_t)(bm * 256) * 1600;
  const unsigned short* bbase0 = Wxt + (size_t)(bn * 256) * 1600;

  // staging geometry: tile-operand = 1024 chunks of 16B ([256 rows][4 kc])
  const int c0 = w * 64 + l;        // round 0 chunk
  const int r0 = c0 >> 2, k0 = c0 & 3;
  const int c1 = 512 + c0;          // round 1 chunk
  const int r1 = c1 >> 2, k1 = c1 & 3;
  const int dst0 = w * 1024;        // + slot base (+ r*8192)
  const int dst1 = 8192 + w * 1024;

#define STAGE(kt2, slot)                                                        \
  {                                                                             \
    const unsigned short* ab = abase0 + (kt2) * 32;                             \
    const unsigned short* bb = bbase0 + (kt2) * 32;                             \
    char* Asl = smem + (slot) * 16384;                                          \
    char* Bsl = smem + 49152 + (slot) * 16384;                                  \
    gload_lds16(ab + (size_t)r0 * 1600 + k0 * 8, Asl + dst0);                   \
    gload_lds16(bb + (size_t)r0 * 1600 + k0 * 8, Bsl + dst0);                   \
    gload_lds16(ab + (size_t)r1 * 1600 + k1 * 8, Asl + dst1);                   \
    gload_lds16(bb + (size_t)r1 * 1600 + k1 * 8, Bsl + dst1);                   \
  }

  f32x4 acc[8][4];
#pragma unroll
  for (int i = 0; i < 8; ++i)
#pragma unroll
    for (int j = 0; j < 4; ++j) acc[i][j] = (f32x4){0.f, 0.f, 0.f, 0.f};

  // prologue: fill the 3-deep pipeline (12 loads/thread outstanding)
  STAGE(0, 0);
  STAGE(1, 1);
  STAGE(2, 2);

  int slot = 0;
  for (int t = 0; t < 50; ++t) {
    // tile t landed when <= 8 newer loads (tiles t+1, t+2) remain in flight
    if (t < 48) {
      asm volatile("s_waitcnt vmcnt(8)" ::: "memory");
    } else {
      asm volatile("s_waitcnt vmcnt(0)" ::: "memory");
    }
    __builtin_amdgcn_s_barrier();
    // register frags from slot (A: 8 x 16B, B: 4 x 16B)
    const char* Asl = smem + slot * 16384;
    const char* Bsl = smem + 49152 + slot * 16384;
    short8 af[8], bf[4];
#pragma unroll
    for (int mf = 0; mf < 8; ++mf)
      af[mf] = *(const short8*)(Asl + (wm * 128 + mf * 16 + l15) * 64 + l4 * 16);
#pragma unroll
    for (int nf = 0; nf < 4; ++nf)
      bf[nf] = *(const short8*)(Bsl + (wn * 64 + nf * 16 + l15) * 64 + l4 * 16);
    asm volatile("s_waitcnt lgkmcnt(0)" ::: "memory");
    __builtin_amdgcn_sched_barrier(0);
    __builtin_amdgcn_s_barrier();  // all waves done reading slot -> reusable
    if (t + 3 < 50) STAGE(t + 3, slot);
    __builtin_amdgcn_s_setprio(1);
#pragma unroll
    for (int mf = 0; mf < 8; ++mf)
#pragma unroll
      for (int nf = 0; nf < 4; ++nf)
        acc[mf][nf] = __builtin_amdgcn_mfma_f32_16x16x32_bf16(
            af[mf], bf[nf], acc[mf][nf], 0, 0, 0);
    __builtin_amdgcn_s_setprio(0);
    slot = (slot == 2) ? 0 : slot + 1;
  }
#undef STAGE

  // epilogue: + bias, permute cols, store f16
#pragma unroll
  for (int nf = 0; nf < 4; ++nf) {
    int col = bn * 256 + wn * 64 + nf * 16 + l15;
    float bs = bsum[col];
    int colp = (col & 1023) * 4 + (col >> 10);
#pragma unroll
    for (int mf = 0; mf < 8; ++mf) {
      int row0 = bm * 256 + wm * 128 + mf * 16 + l4 * 4;
#pragma unroll
      for (int j = 0; j < 4; ++j)
        gx[(size_t)(row0 + j) * 4096 + colp] = (_Float16)(acc[mf][nf][j] + bs);
    }
  }
}

// ---------------- K5: persistent LSTM recurrence (R12 + spread flags) -------
// 8 groups (gg=blockIdx&7) x 32 WGs (cwg), 512 thr, 96KB LDS -> 1 WG/CU.
// Wave w: ws=w&1 (h-col half), kq=w>>1 (K-slice of 256). Per step:
//   wave7 relay-polls the 32 per-WG flags (each on its OWN 128B line) ->
//   syncA -> batched cooperative 16KB h stage (2 x dwordx4 sc0sc1, one
//   vmcnt(0), 2 swizzled 16B ds_writes) -> gx loads (finalizer lanes) ->
//   syncB -> 32 MFMAs (kq K-split x 4-gate A reuse) -> partials to LDS ->
//   syncC -> finalizers (kq=0) reduce + gates + h-store -> vmcnt(0) ->
//   syncD -> tid0 stores single per-WG flag (own line).
__global__ __launch_bounds__(512, 2) void lstm_seq(
    const _Float16* __restrict__ gx, const unsigned short* __restrict__ Wht,
    const float* __restrict__ subj, const float* __restrict__ Winit,
    const float* __restrict__ binit, float* __restrict__ out,
    unsigned int* __restrict__ hbuf, unsigned int* __restrict__ bar) {
  const int gg  = blockIdx.x & 7;
  const int cwg = blockIdx.x >> 3;
  const int tid = threadIdx.x;
  const int w = tid >> 6, l = tid & 63;
  const int l15 = l & 15, l4 = l >> 4;
  const int ws = w & 1, kq = w >> 1;
  const int ghc = cwg * 32 + ws * 16 + l15;  // this lane's h-col (B operand)

  __shared__ __align__(16) char smem[98304];  // 96 KB -> exclusive CU

  // Wh B-fragments (128 VGPR), resident across all 512 steps
  short8 Bf[32];
  {
    const unsigned short* wp =
        Wht + (size_t)(cwg * 32 + ws * 16 + l15) * 1024 + kq * 256 + l4 * 8;
#pragma unroll
    for (int g = 0; g < 4; ++g)
#pragma unroll
      for (int ks = 0; ks < 8; ++ks)
        Bf[g * 8 + ks] = *(const short8*)(wp + (size_t)g * 1048576 + ks * 32);
  }

  // c0 = subject_id @ W_init + b_init (finalizer lanes only)
  float c[4], hq[4][8];
  if (w < 2 && l4 < 2) {
#pragma unroll
    for (int j = 0; j < 4; ++j) {
      int b = gg * 8 + l4 * 4 + j;
      float a = binit[ghc];
      for (int k = 0; k < 87; ++k) a += subj[b * 87 + k] * Winit[k * 1024 + ghc];
      c[j] = a;
    }
  }

  unsigned int* flags = bar + gg * 1024;  // 32 WGs x 32-u32 stride (128B/line)

  // batched stage addressing: 16B chunks tid and tid+512 (1024 total = 16KB)
  const int so0 = tid * 16;
  const int so1 = (tid + 512) * 16;
  const int sw0 = so0 ^ (((so0 >> 11) & 7) << 4);
  const int sw1 = so1 ^ (((so1 >> 11) & 7) << 4);

  for (int t8 = 0; t8 < 64; ++t8) {
#pragma unroll
    for (int s = 0; s < 8; ++s) {
      const int t = t8 * 8 + s;
      const int cur = s & 1, nxt = cur ^ 1;
      // 1. poll: wave 7's 32 lanes read the 32 WG flags (distinct lines)
      if (w == 7) {
        const unsigned tgt = (unsigned)t;
        for (;;) {
          unsigned f = 0xFFFFFFFFu;
          if (l < 32)
            f = __hip_atomic_load(flags + l * 32, __ATOMIC_RELAXED,
                                  __HIP_MEMORY_SCOPE_AGENT);
          if (__all(f >= tgt)) break;
          __builtin_amdgcn_s_sleep(1);
        }
      }
      __syncthreads();  // A: h(t) visible to all
      // 2. batched cooperative stage: 2 x 16B loads, one drain, swizzled writes
      {
        const char* src = (const char*)hbuf + (size_t)(gg * 2 + cur) * 16384;
        u32x4 v0 = h_load16(src + so0);
        u32x4 v1 = h_load16(src + so1);
        asm volatile("s_waitcnt vmcnt(0)" ::: "memory");
        *(u32x4*)(smem + sw0) = v0;
        *(u32x4*)(smem + sw1) = v1;
      }
      // 3. gx loads (finalizer lanes; consumed after sync C)
      f16x4 gxq[4];
      if (w < 2 && l4 < 2) {
        const _Float16* gp =
            gx + ((size_t)(t * 64 + gg * 8 + l4 * 4)) * 4096 + ghc * 4;
#pragma unroll
        for (int j = 0; j < 4; ++j) gxq[j] = *(const f16x4*)(gp + (size_t)j * 4096);
      }
      __syncthreads();  // B: staged h readable
      // 4. MFMA: 8 A-reads, each feeds 4 gate-MFMAs
      f32x4 acc[4];
#pragma unroll
      for (int g = 0; g < 4; ++g) acc[g] = (f32x4){0.f, 0.f, 0.f, 0.f};
#pragma unroll
      for (int ks = 0; ks < 8; ++ks) {
        short8 a = *(const short8*)(
            smem + (((l15 & 7) * 2048 + kq * 512 + ks * 64 + l4 * 16) ^ ((l15 & 7) << 4)));
#pragma unroll
        for (int g = 0; g < 4; ++g)
          acc[g] = __builtin_amdgcn_mfma_f32_16x16x32_bf16(a, Bf[g * 8 + ks], acc[g], 0, 0, 0);
      }
      // 5. K-partials to LDS (waves kq>0)
      if (w >= 2) {
        char* pb = smem + 16384 + (size_t)(ws * 3 + kq - 1) * 4096;
#pragma unroll
        for (int g = 0; g < 4; ++g) *(f32x4*)(pb + g * 1024 + l * 16) = acc[g];
      }
      __syncthreads();  // C: partials readable
      // 6. reduce + gates + h-store (finalizer waves kq=0)
      if (w < 2) {
        f32x4 red[4];
#pragma unroll
        for (int g = 0; g < 4; ++g) {
          red[g] = acc[g];
#pragma unroll
          for (int kk = 0; kk < 3; ++kk)
            red[g] += *(const f32x4*)(smem + 16384 + (size_t)(ws * 3 + kk) * 4096 +
                                      g * 1024 + l * 16);
        }
        if (l4 < 2) {
#pragma unroll
          for (int j = 0; j < 4; ++j) {
            float fv = sigm(red[0][j] + (float)gxq[j][0]);
            float iv = sigm(red[1][j] + (float)gxq[j][1]);
            float uv = tanh_(red[2][j] + (float)gxq[j][2]);
            float ov = sigm(red[3][j] + (float)gxq[j][3]);
            c[j] = c[j] * fv + iv * uv;
            float hv = ov * tanh_(c[j]);
            hq[j][s] = hv;
            float hn = __shfl_xor(hv, 1);  // neighbor h-col for u32 packing
            if (!(l15 & 1)) {
              unsigned int pk = (unsigned int)f2bf(hv) | ((unsigned int)f2bf(hn) << 16);
              __hip_atomic_store(
                  hbuf + (gg * 2 + nxt) * 4096 + (l4 * 4 + j) * 512 +
                      cwg * 16 + ws * 8 + (l15 >> 1),
                  pk, __ATOMIC_RELAXED, __HIP_MEMORY_SCOPE_AGENT);
            }
          }
        }
      }
      asm volatile("s_waitcnt vmcnt(0)" ::: "memory");  // drain h-stores
      __syncthreads();  // D: both finalizer waves drained
      if (tid == 0)
        __hip_atomic_store(flags + cwg * 32, (unsigned)(t + 1),
                           __ATOMIC_RELAXED, __HIP_MEMORY_SCOPE_AGENT);
    }
    // flush 8-step h_seq window (32B chunks per lane)
    if (w < 2 && l4 < 2) {
      int tb = t8 * 8;
#pragma unroll
      for (int j = 0; j < 4; ++j) {
        f32x4 v0 = {hq[j][0], hq[j][1], hq[j][2], hq[j][3]};
        f32x4 v1 = {hq[j][4], hq[j][5], hq[j][6], hq[j][7]};
        float* op = out + (size_t)(gg * 8 + l4 * 4 + j) * 524288 + (size_t)ghc * 512 + tb;
        *(f32x4*)op = v0;
        *(f32x4*)(op + 4) = v1;
      }
    }
  }
  if (w < 2 && l4 < 2) {  // c_fin
#pragma unroll
    for (int j = 0; j < 4; ++j)
      out[33554432 + (size_t)(gg * 8 + l4 * 4 + j) * 1024 + ghc] = c[j];
  }
}

// ---------------- launch ----------------
extern "C" void kernel_launch(void* const* d_in, const int* in_sizes, int n_in,
                              void* d_out, int out_size, void* d_ws, size_t ws_size,
                              hipStream_t stream) {
  (void)in_sizes; (void)n_in; (void)out_size;
  if (ws_size < WS_NEED) return;

  const float* x     = (const float*)d_in[0];
  const float* y     = (const float*)d_in[1];
  const float* subj  = (const float*)d_in[2];
  const float* W_fx  = (const float*)d_in[3];
  const float* b_fx  = (const float*)d_in[4];
  const float* W_fh  = (const float*)d_in[5];
  const float* b_fh  = (const float*)d_in[6];
  const float* W_ix  = (const float*)d_in[7];
  const float* b_ix  = (const float*)d_in[8];
  const float* W_ih  = (const float*)d_in[9];
  const float* b_ih  = (const float*)d_in[10];
  const float* W_ux  = (const float*)d_in[11];
  const float* b_ux  = (const float*)d_in[12];
  const float* W_uh  = (const float*)d_in[13];
  const float* b_uh  = (const float*)d_in[14];
  const float* W_ox  = (const float*)d_in[15];
  const float* b_ox  = (const float*)d_in[16];
  const float* W_oh  = (const float*)d_in[17];
  const float* b_oh  = (const float*)d_in[18];
  const float* Winit = (const float*)d_in[19];
  const float* binit = (const float*)d_in[20];
  float* out = (float*)d_out;

  char* ws = (char*)d_ws;
  unsigned short* Wxt  = (unsigned short*)(ws + OFF_WXT);
  unsigned short* Wht  = (unsigned short*)(ws + OFF_WHT);
  float*          bsum = (float*)(ws + OFF_BSUM);
  unsigned int*   xs32 = (unsigned int*)(ws + OFF_XS);
  _Float16*       gx   = (_Float16*)(ws + OFF_GX);
  unsigned int*   hbuf = (unsigned int*)(ws + OFF_HBUF);
  unsigned int*   bar  = (unsigned int*)(ws + OFF_BAR);

  // deterministic per-call init: h(0)=0 in both buffers, flags=0
  hipMemsetAsync(ws + OFF_HBUF, 0, WS_NEED - OFF_HBUF, stream);

  pack_w<<<dim3(50, 128), 256, 0, stream>>>(W_fx, W_ix, W_ux, W_ox, Wxt, 1600);
  pack_w<<<dim3(32, 128), 256, 0, stream>>>(W_fh, W_ih, W_uh, W_oh, Wht, 1024);
  pack_bias<<<16, 256, 0, stream>>>(b_fx, b_ix, b_ux, b_ox, b_fh, b_ih, b_uh, b_oh, bsum);
  xs_pack<<<dim3(16, 25, 64), 256, 0, stream>>>(x, y, xs32);
  gemm_gx<<<2048, 512, 0, stream>>>((const unsigned short*)xs32, Wxt, bsum, gx);

  const _Float16* gxc = gx;
  const unsigned short* whtc = Wht;
  void* ka[8] = {(void*)&gxc, (void*)&whtc, (void*)&subj, (void*)&Winit,
                 (void*)&binit, (void*)&out, (void*)&hbuf, (void*)&bar};
  hipError_t e = hipLaunchCooperativeKernel((const void*)lstm_seq, dim3(256), dim3(512),
                                            ka, 0, stream);
  if (e != hipSuccess) {
    // fallback: plain launch; 256 WGs at 1 WG/CU (96KB LDS) co-resident on 256 CUs
    lstm_seq<<<256, 512, 0, stream>>>(gxc, whtc, subj, Winit, binit, out, hbuf, bar);
  }
}